// Round 1
// baseline (182.063 us; speedup 1.0000x reference)
//
#include <hip/hip_runtime.h>
#include <hip/hip_bf16.h>
#include <math.h>

// Problem constants
#define BB 2
#define NN 2048
#define DD 512
#define HH 8
#define VD 64

typedef _Float16 half8 __attribute__((ext_vector_type(8)));
typedef _Float16 half4 __attribute__((ext_vector_type(4)));
typedef float f32x4 __attribute__((ext_vector_type(4)));

// ---------------------------------------------------------------------------
// Kernel 1: convert weights fp32 [H][D][VD] -> f16 transposed Wt[3][H][VD][D]
// ---------------------------------------------------------------------------
__global__ __launch_bounds__(256) void wconv_kernel(
    const float* __restrict__ qw, const float* __restrict__ kw,
    const float* __restrict__ vw, _Float16* __restrict__ wt)
{
    int idx = blockIdx.x * 256 + threadIdx.x;   // flat over [3][H][VD][D]
    int k = idx & (DD - 1);
    int o = (idx >> 9) & (VD - 1);
    int h = (idx >> 15) & (HH - 1);
    int t = idx >> 18;
    const float* src = (t == 0) ? qw : (t == 1) ? kw : vw;
    wt[idx] = (_Float16)src[(h * DD + k) * VD + o];
}

// ---------------------------------------------------------------------------
// Kernel 2: QKV projection.
//   X [B*N][D] fp32  x  Wt [3][H][VD][D] f16  ->
//   Qs [B*H][N][VD] (scaled 1/8), Kb [B*H][N][VD], Vt [B*H][VD][N]   (f16)
// Block: 256 thr (4 waves). Each block: one 64-row m-tile x one head, all 3 types.
// mfma_f32_16x16x32_f16: A row = lane&15, k = 8*(lane>>4)+i;
//                        B k = 8*(lane>>4)+i, col = lane&15;
//                        D col = lane&15, row = 4*(lane>>4)+i   (m89-verified)
// ---------------------------------------------------------------------------
__global__ __launch_bounds__(256) void qkv_proj_kernel(
    const float* __restrict__ x,
    const _Float16* __restrict__ wt,
    _Float16* __restrict__ qs,
    _Float16* __restrict__ kb,
    _Float16* __restrict__ vt)
{
    __shared__ __align__(16) _Float16 xs[64][72];   // +8 pad: 2-way bank alias only
    const int t = threadIdx.x;
    const int wave = t >> 6, lane = t & 63;
    const int lq = lane & 15, g = lane >> 4;
    const int m0 = blockIdx.x * 64;   // row base in [0, B*N)
    const int h  = blockIdx.y;

    f32x4 acc[3][4];
    for (int ty = 0; ty < 3; ++ty)
        for (int ct = 0; ct < 4; ++ct) acc[ty][ct] = (f32x4){0.f, 0.f, 0.f, 0.f};

    for (int ks = 0; ks < DD / 64; ++ks) {
        // stage 64x64 fp32 X tile -> f16 LDS, coalesced float4 loads
        for (int j = 0; j < 4; ++j) {
            int idx = t + 256 * j;            // 0..1023 float4 slots
            int row = idx >> 4, c4 = idx & 15;
            const float4 xv = *(const float4*)(x + (size_t)(m0 + row) * DD + ks * 64 + c4 * 4);
            half4 hv;
            hv[0] = (_Float16)xv.x; hv[1] = (_Float16)xv.y;
            hv[2] = (_Float16)xv.z; hv[3] = (_Float16)xv.w;
            *(half4*)&xs[row][c4 * 4] = hv;
        }
        __syncthreads();
        half8 af0 = *(const half8*)&xs[16 * wave + lq][8 * g];
        half8 af1 = *(const half8*)&xs[16 * wave + lq][32 + 8 * g];
        for (int ty = 0; ty < 3; ++ty) {
            const _Float16* wbase = wt + ((size_t)ty * HH + h) * VD * DD;
            for (int ct = 0; ct < 4; ++ct) {
                const _Float16* wp = wbase + (size_t)(ct * 16 + lq) * DD + ks * 64 + 8 * g;
                half8 b0 = *(const half8*)(wp);
                half8 b1 = *(const half8*)(wp + 32);
                acc[ty][ct] = __builtin_amdgcn_mfma_f32_16x16x32_f16(af0, b0, acc[ty][ct], 0, 0, 0);
                acc[ty][ct] = __builtin_amdgcn_mfma_f32_16x16x32_f16(af1, b1, acc[ty][ct], 0, 0, 0);
            }
        }
        __syncthreads();
    }
    // epilogue: D col = lq + 16*ct (o), row = 16*wave + 4*g + i (n)
    for (int ct = 0; ct < 4; ++ct) {
        int o = ct * 16 + lq;
        for (int i = 0; i < 4; ++i) {
            int ng = m0 + 16 * wave + 4 * g + i;
            int b = ng >> 11, nb = ng & (NN - 1);
            size_t bh = (size_t)(b * HH + h);
            qs[(bh * NN + nb) * VD + o] = (_Float16)(acc[0][ct][i] * 0.125f);
            kb[(bh * NN + nb) * VD + o] = (_Float16)(acc[1][ct][i]);
            vt[(bh * VD + o) * NN + nb] = (_Float16)(acc[2][ct][i]);
        }
    }
}

// ---------------------------------------------------------------------------
// Kernel 3: fused flash attention + GELU.
// Grid (N/64, B*H), block 256 (4 waves). Wave owns 16 q rows.
// Swapped operands: S^T = K * Q^T  (lane's col = q = lane&15 for all 16 regs)
//                   O^T = V^T * P^T (same q-column frame -> no stat broadcasts)
// ---------------------------------------------------------------------------
__global__ __launch_bounds__(256) void attn_kernel(
    const _Float16* __restrict__ qs,   // [BH][N][VD], pre-scaled by 1/8
    const _Float16* __restrict__ kb,   // [BH][N][VD]
    const _Float16* __restrict__ vt,   // [BH][VD][N]
    float* __restrict__ out)           // [B][N][H*VD]
{
    __shared__ __align__(16) _Float16 pls[4][16][72];  // wave-private P[q][kv], padded
    const int t = threadIdx.x;
    const int wave = t >> 6, lane = t & 63;
    const int lq = lane & 15, g = lane >> 4;
    const int bh = blockIdx.y;
    const int qrow = blockIdx.x * 64 + wave * 16 + lq;  // n (within batch) of this lane's q-column

    const _Float16* qp = qs + ((size_t)bh * NN + qrow) * VD + 8 * g;
    half8 qf0 = *(const half8*)qp;
    half8 qf1 = *(const half8*)(qp + 32);

    const _Float16* kbase = kb + (size_t)bh * NN * VD;
    const _Float16* vbase = vt + (size_t)bh * VD * NN;

    f32x4 oacc[4];
    for (int mt = 0; mt < 4; ++mt) oacc[mt] = (f32x4){0.f, 0.f, 0.f, 0.f};
    float mrun = -INFINITY, lsum = 0.f;

    for (int kv0 = 0; kv0 < NN; kv0 += 64) {
        // S^T tile [64 kv][16 q] as 4 mfma D-frags
        f32x4 s[4];
        for (int mt = 0; mt < 4; ++mt) s[mt] = (f32x4){0.f, 0.f, 0.f, 0.f};
        for (int mt = 0; mt < 4; ++mt) {
            const _Float16* kp = kbase + (size_t)(kv0 + mt * 16 + lq) * VD + 8 * g;
            half8 k0 = *(const half8*)kp;
            half8 k1 = *(const half8*)(kp + 32);
            s[mt] = __builtin_amdgcn_mfma_f32_16x16x32_f16(k0, qf0, s[mt], 0, 0, 0);
            s[mt] = __builtin_amdgcn_mfma_f32_16x16x32_f16(k1, qf1, s[mt], 0, 0, 0);
        }
        // online softmax over this tile's 64 kv, per q-column (= lq)
        float tmax = s[0][0];
        for (int mt = 0; mt < 4; ++mt)
            for (int i = 0; i < 4; ++i) tmax = fmaxf(tmax, s[mt][i]);
        tmax = fmaxf(tmax, __shfl_xor(tmax, 16, 64));
        tmax = fmaxf(tmax, __shfl_xor(tmax, 32, 64));
        float mnew = fmaxf(mrun, tmax);
        float corr = __expf(mrun - mnew);   // first tile: exp(-inf) = 0
        float psum = 0.f;
        for (int mt = 0; mt < 4; ++mt) {
            half4 pv;
            for (int i = 0; i < 4; ++i) {
                float p = __expf(s[mt][i] - mnew);
                psum += p;
                pv[i] = (_Float16)p;
            }
            // lane holds kv = 16*mt + 4*g + i  -> pack 4 and write 8B
            *(half4*)&pls[wave][lq][mt * 16 + 4 * g] = pv;
        }
        psum += __shfl_xor(psum, 16, 64);
        psum += __shfl_xor(psum, 32, 64);
        lsum = lsum * corr + psum;
        mrun = mnew;
        for (int mt = 0; mt < 4; ++mt)
            for (int i = 0; i < 4; ++i) oacc[mt][i] *= corr;
        asm volatile("s_waitcnt lgkmcnt(0)" ::: "memory");
        // O^T += V^T * P^T
        for (int kc = 0; kc < 2; ++kc) {
            half8 pf = *(const half8*)&pls[wave][lq][kc * 32 + 8 * g];
            for (int mt = 0; mt < 4; ++mt) {
                const _Float16* vp = vbase + (size_t)(mt * 16 + lq) * NN + kv0 + kc * 32 + 8 * g;
                half8 vf = *(const half8*)vp;
                oacc[mt] = __builtin_amdgcn_mfma_f32_16x16x32_f16(vf, pf, oacc[mt], 0, 0, 0);
            }
        }
    }

    // epilogue: O^T row = d = 16*mt + 4*g + i, col = q = lq. Normalize + exact GELU.
    float inv = 1.f / lsum;
    const int b = bh >> 3, h = bh & 7;
    float* op = out + ((size_t)b * NN + qrow) * (HH * VD) + h * VD;
    for (int mt = 0; mt < 4; ++mt) {
        float4 r;
        float v0 = oacc[mt][0] * inv, v1 = oacc[mt][1] * inv;
        float v2 = oacc[mt][2] * inv, v3 = oacc[mt][3] * inv;
        r.x = 0.5f * v0 * (1.f + erff(v0 * 0.70710678118654752f));
        r.y = 0.5f * v1 * (1.f + erff(v1 * 0.70710678118654752f));
        r.z = 0.5f * v2 * (1.f + erff(v2 * 0.70710678118654752f));
        r.w = 0.5f * v3 * (1.f + erff(v3 * 0.70710678118654752f));
        *(float4*)(op + mt * 16 + 4 * g) = r;
    }
}

// ---------------------------------------------------------------------------
extern "C" void kernel_launch(void* const* d_in, const int* in_sizes, int n_in,
                              void* d_out, int out_size, void* d_ws, size_t ws_size,
                              hipStream_t stream)
{
    const float* x  = (const float*)d_in[0];
    const float* qw = (const float*)d_in[1];
    const float* kw = (const float*)d_in[2];
    const float* vw = (const float*)d_in[3];
    float* out = (float*)d_out;

    // workspace layout (f16 elements)
    _Float16* wt  = (_Float16*)d_ws;            // [3][H][VD][D]   = 786432
    _Float16* qsp = wt  + 786432;               // [B*H][N][VD]    = 2097152
    _Float16* kbp = qsp + 2097152;              // [B*H][N][VD]
    _Float16* vtp = kbp + 2097152;              // [B*H][VD][N]

    hipLaunchKernelGGL(wconv_kernel, dim3(786432 / 256), dim3(256), 0, stream,
                       qw, kw, vw, wt);
    hipLaunchKernelGGL(qkv_proj_kernel, dim3((BB * NN) / 64, HH), dim3(256), 0, stream,
                       x, wt, qsp, kbp, vtp);
    hipLaunchKernelGGL(attn_kernel, dim3(NN / 64, BB * HH), dim3(256), 0, stream,
                       qsp, kbp, vtp, out);
}

// Round 2
// 68.452 us; speedup vs baseline: 2.6597x; 2.6597x over previous
//
#include <hip/hip_runtime.h>
#include <hip/hip_bf16.h>
#include <math.h>

// Problem constants
#define BB 2
#define NN 2048
#define DD 512
#define HH 8
#define VD 64

typedef _Float16 half8 __attribute__((ext_vector_type(8)));
typedef _Float16 half4 __attribute__((ext_vector_type(4)));
typedef float f32x4 __attribute__((ext_vector_type(4)));

#define GLDS16(gp, lp) __builtin_amdgcn_global_load_lds( \
    (const __attribute__((address_space(1))) void*)(gp), \
    (__attribute__((address_space(3))) void*)(lp), 16, 0, 0)

// Stage 8 rows x 64 f16 cols (1KB) from global (row stride ldg elems) into LDS
// linear at lbase (wave-uniform), XOR-swizzling bits 4-6 of byte-in-row with
// (row&7). Source address carries the swizzle (global_load_lds dest is linear).
__device__ __forceinline__ void stage8(const _Float16* gsrc, size_t ldg, int r0,
                                       _Float16* lbase, int lane) {
    int r8 = lane >> 3;                       // row within the 8-row group
    int ce = ((lane & 7) ^ r8) << 3;          // swizzled element offset in row
    const _Float16* g = gsrc + (size_t)(r0 + r8) * ldg + ce;
    GLDS16(g, lbase);
}

// Read a swizzled half8 fragment: logical (row, col-byte cb) of a [*][128B] tile.
__device__ __forceinline__ half8 frag_ld(const _Float16* tile, int row, int cb) {
    int off = row * 128 + (cb ^ ((row & 7) << 4));
    return *(const half8*)((const char*)tile + off);
}

// ---------------------------------------------------------------------------
// prep: blocks 0..191  : weight transpose fp32 [H][D][VD] -> f16 Wt[3][H][VD][D]
//       blocks 192..1215: X fp32 -> f16 cast (straight copy)
// ---------------------------------------------------------------------------
__global__ __launch_bounds__(256) void prep_kernel(
    const float* __restrict__ x,
    const float* __restrict__ qw, const float* __restrict__ kw,
    const float* __restrict__ vw,
    _Float16* __restrict__ wt, _Float16* __restrict__ xh)
{
    __shared__ float ls[64][65];
    const int t = threadIdx.x;
    const int bid = blockIdx.x;
    if (bid < 192) {
        // transpose one 64k x 64o tile of one (ty, h)
        const int kc = bid & 7, h = (bid >> 3) & 7, ty = bid >> 6;
        const float* src = (ty == 0) ? qw : (ty == 1) ? kw : vw;
#pragma unroll
        for (int j = 0; j < 4; ++j) {
            int idx = t + 256 * j;
            int k = idx >> 4, o4 = idx & 15;
            float4 v = *(const float4*)(src + ((size_t)(h * DD + kc * 64 + k) * VD + o4 * 4));
            ls[k][o4 * 4 + 0] = v.x; ls[k][o4 * 4 + 1] = v.y;
            ls[k][o4 * 4 + 2] = v.z; ls[k][o4 * 4 + 3] = v.w;
        }
        __syncthreads();
#pragma unroll
        for (int j = 0; j < 4; ++j) {
            int idx = t + 256 * j;
            int o = idx >> 4, k4 = idx & 15;
            half4 hv;
#pragma unroll
            for (int i = 0; i < 4; ++i) hv[i] = (_Float16)ls[k4 * 4 + i][o];
            *(half4*)(wt + ((size_t)(ty * HH + h) * VD + o) * DD + kc * 64 + k4 * 4) = hv;
        }
    } else {
        size_t idx = ((size_t)(bid - 192) * 256 + t) * 8;
        float4 a = *(const float4*)(x + idx);
        float4 b = *(const float4*)(x + idx + 4);
        half8 hv;
        hv[0] = (_Float16)a.x; hv[1] = (_Float16)a.y;
        hv[2] = (_Float16)a.z; hv[3] = (_Float16)a.w;
        hv[4] = (_Float16)b.x; hv[5] = (_Float16)b.y;
        hv[6] = (_Float16)b.z; hv[7] = (_Float16)b.w;
        *(half8*)(xh + idx) = hv;
    }
}

// ---------------------------------------------------------------------------
// QKV projection: Xh [B*N][D] f16 x Wt [3][H][VD][D] f16 ->
//   Qs [BH][N][VD] (x0.125), Kb [BH][N][VD], Vt [BH][VD][N]
// Block (4 waves): 64-row m-tile x one head, all 3 types (192 out cols).
// Wave owns a 32x96 quadrant. X + W tiles double-buffered in LDS (swizzled).
// ---------------------------------------------------------------------------
__global__ __launch_bounds__(256) void qkv_proj_kernel(
    const _Float16* __restrict__ xh,
    const _Float16* __restrict__ wt,
    _Float16* __restrict__ qsp,
    _Float16* __restrict__ kbp,
    _Float16* __restrict__ vtp)
{
    __shared__ __align__(16) _Float16 xls[2][4096];    // 64 x 64, 8KB each
    __shared__ __align__(16) _Float16 wls[2][12288];   // 192 x 64, 24KB each
    const int t = threadIdx.x;
    const int wave = t >> 6, lane = t & 63;
    const int lq = lane & 15, g = lane >> 4;
    const int bid = blockIdx.x;
    const int h = bid & 7;                 // head -> XCD locality for weights
    const int m0 = (bid >> 3) * 64;
    const int rbase = 32 * (wave >> 1);
    const int cbase = 96 * (wave & 1);

    f32x4 acc[2][6];
#pragma unroll
    for (int a = 0; a < 2; ++a)
#pragma unroll
        for (int c = 0; c < 6; ++c) acc[a][c] = (f32x4){0.f, 0.f, 0.f, 0.f};

    auto stage = [&](int buf, int ks) {
#pragma unroll
        for (int j = 0; j < 2; ++j) {
            int i = wave * 2 + j;
            stage8(xh + (size_t)m0 * DD + ks * 64, DD, i * 8, &xls[buf][i * 512], lane);
        }
#pragma unroll
        for (int j = 0; j < 6; ++j) {
            int i = wave * 6 + j;
            int ty = i >> 3;
            int ol = (i & 7) * 8;
            stage8(wt + ((size_t)(ty * HH + h) * VD + ol) * DD + ks * 64, DD, 0,
                   &wls[buf][i * 512], lane);
        }
    };

    stage(0, 0);
    __syncthreads();
    int buf = 0;
    for (int ks = 0; ks < 8; ++ks) {
        if (ks < 7) stage(buf ^ 1, ks + 1);
        half8 af[2][2];
#pragma unroll
        for (int amt = 0; amt < 2; ++amt) {
            af[amt][0] = frag_ld(xls[buf], rbase + amt * 16 + lq, 16 * g);
            af[amt][1] = frag_ld(xls[buf], rbase + amt * 16 + lq, 64 + 16 * g);
        }
#pragma unroll
        for (int ct = 0; ct < 6; ++ct) {
            int wr = cbase + ct * 16 + lq;
            half8 bf0 = frag_ld(wls[buf], wr, 16 * g);
            half8 bf1 = frag_ld(wls[buf], wr, 64 + 16 * g);
#pragma unroll
            for (int amt = 0; amt < 2; ++amt) {
                acc[amt][ct] = __builtin_amdgcn_mfma_f32_16x16x32_f16(af[amt][0], bf0, acc[amt][ct], 0, 0, 0);
                acc[amt][ct] = __builtin_amdgcn_mfma_f32_16x16x32_f16(af[amt][1], bf1, acc[amt][ct], 0, 0, 0);
            }
        }
        __syncthreads();
        buf ^= 1;
    }

#pragma unroll
    for (int ct = 0; ct < 6; ++ct) {
        int gcol = cbase + ct * 16 + lq;    // 0..191
        int ty = gcol >> 6, o = gcol & 63;
#pragma unroll
        for (int amt = 0; amt < 2; ++amt) {
#pragma unroll
            for (int i = 0; i < 4; ++i) {
                int ng = m0 + rbase + amt * 16 + 4 * g + i;
                int b = ng >> 11, nb = ng & (NN - 1);
                size_t bh = (size_t)(b * HH + h);
                float v = acc[amt][ct][i];
                if (ty == 0)      qsp[(bh * NN + nb) * VD + o] = (_Float16)(v * 0.125f);
                else if (ty == 1) kbp[(bh * NN + nb) * VD + o] = (_Float16)v;
                else              vtp[(bh * VD + o) * NN + nb] = (_Float16)v;
            }
        }
    }
}

// ---------------------------------------------------------------------------
// Fused flash attention + GELU. Grid flat 512 (XCD-remapped), block 256.
// Wave owns 16 q rows. K/V tiles double-buffered in swizzled LDS via
// global_load_lds; one barrier per kv-iter; prefetch issued before compute.
// Swapped operands: S^T = K*Q^T, O^T = V^T*P^T (q = lane&15 throughout).
// ---------------------------------------------------------------------------
__global__ __launch_bounds__(256) void attn_kernel(
    const _Float16* __restrict__ qs,   // [BH][N][VD], pre-scaled 1/8
    const _Float16* __restrict__ kb,   // [BH][N][VD]
    const _Float16* __restrict__ vt,   // [BH][VD][N]
    float* __restrict__ out)           // [B][N][H*VD]
{
    __shared__ __align__(16) _Float16 kls[2][4096];    // [kv=64][d=64] swizzled
    __shared__ __align__(16) _Float16 vls[2][4096];    // [d=64][kv=64] swizzled
    __shared__ __align__(16) _Float16 pls[4][16][72];  // wave-private P
    const int t = threadIdx.x;
    const int wave = t >> 6, lane = t & 63;
    const int lq = lane & 15, g = lane >> 4;
    const int bid = blockIdx.x;
    const int bh = (bid & 7) * 2 + ((bid >> 3) & 1);   // 2 heads per XCD
    const int qt = bid >> 4;
    const int qrow = qt * 64 + wave * 16 + lq;

    const _Float16* qp = qs + ((size_t)bh * NN + qrow) * VD + 8 * g;
    half8 qf0 = *(const half8*)qp;
    half8 qf1 = *(const half8*)(qp + 32);

    const _Float16* kbase = kb + (size_t)bh * NN * VD;
    const _Float16* vbase = vt + (size_t)bh * VD * NN;

    auto stage_kv = [&](int buf, int kv0) {
#pragma unroll
        for (int j = 0; j < 2; ++j) {
            int i = wave * 2 + j;
            stage8(kbase + (size_t)kv0 * VD, VD, i * 8, &kls[buf][i * 512], lane);
            stage8(vbase + kv0, NN, i * 8, &vls[buf][i * 512], lane);
        }
    };

    f32x4 oacc[4];
#pragma unroll
    for (int mt = 0; mt < 4; ++mt) oacc[mt] = (f32x4){0.f, 0.f, 0.f, 0.f};
    float mrun = -INFINITY, lsum = 0.f;

    stage_kv(0, 0);
    __syncthreads();
    int buf = 0;
    for (int it = 0; it < NN / 64; ++it) {
        if (it < NN / 64 - 1) stage_kv(buf ^ 1, (it + 1) * 64);
        // S^T tile [64 kv][16 q]
        f32x4 s[4];
#pragma unroll
        for (int mt = 0; mt < 4; ++mt) s[mt] = (f32x4){0.f, 0.f, 0.f, 0.f};
#pragma unroll
        for (int mt = 0; mt < 4; ++mt) {
            half8 k0 = frag_ld(kls[buf], mt * 16 + lq, 16 * g);
            half8 k1 = frag_ld(kls[buf], mt * 16 + lq, 64 + 16 * g);
            s[mt] = __builtin_amdgcn_mfma_f32_16x16x32_f16(k0, qf0, s[mt], 0, 0, 0);
            s[mt] = __builtin_amdgcn_mfma_f32_16x16x32_f16(k1, qf1, s[mt], 0, 0, 0);
        }
        // online softmax per q-column (= lq)
        float tmax = s[0][0];
#pragma unroll
        for (int mt = 0; mt < 4; ++mt)
#pragma unroll
            for (int i = 0; i < 4; ++i) tmax = fmaxf(tmax, s[mt][i]);
        tmax = fmaxf(tmax, __shfl_xor(tmax, 16, 64));
        tmax = fmaxf(tmax, __shfl_xor(tmax, 32, 64));
        float mnew = fmaxf(mrun, tmax);
        float corr = __expf(mrun - mnew);
        float psum = 0.f;
#pragma unroll
        for (int mt = 0; mt < 4; ++mt) {
            half4 pv;
#pragma unroll
            for (int i = 0; i < 4; ++i) {
                float p = __expf(s[mt][i] - mnew);
                psum += p;
                pv[i] = (_Float16)p;
            }
            *(half4*)&pls[wave][lq][mt * 16 + 4 * g] = pv;
        }
        psum += __shfl_xor(psum, 16, 64);
        psum += __shfl_xor(psum, 32, 64);
        lsum = lsum * corr + psum;
        mrun = mnew;
#pragma unroll
        for (int mt = 0; mt < 4; ++mt)
#pragma unroll
            for (int i = 0; i < 4; ++i) oacc[mt][i] *= corr;
        asm volatile("s_waitcnt lgkmcnt(0)" ::: "memory");
        // O^T += V^T * P^T
#pragma unroll
        for (int kc = 0; kc < 2; ++kc) {
            half8 pf = *(const half8*)&pls[wave][lq][kc * 32 + 8 * g];
#pragma unroll
            for (int mt = 0; mt < 4; ++mt) {
                half8 vf = frag_ld(vls[buf], mt * 16 + lq, kc * 64 + 16 * g);
                oacc[mt] = __builtin_amdgcn_mfma_f32_16x16x32_f16(vf, pf, oacc[mt], 0, 0, 0);
            }
        }
        __syncthreads();
        buf ^= 1;
    }

    // epilogue: row = d = 16*mt + 4*g + i, col = q = lq. Normalize + exact GELU.
    float inv = 1.f / lsum;
    const int b = bh >> 3, h = bh & 7;
    float* op = out + ((size_t)b * NN + qrow) * (HH * VD) + h * VD;
#pragma unroll
    for (int mt = 0; mt < 4; ++mt) {
        float4 r;
        float v0 = oacc[mt][0] * inv, v1 = oacc[mt][1] * inv;
        float v2 = oacc[mt][2] * inv, v3 = oacc[mt][3] * inv;
        r.x = 0.5f * v0 * (1.f + erff(v0 * 0.70710678118654752f));
        r.y = 0.5f * v1 * (1.f + erff(v1 * 0.70710678118654752f));
        r.z = 0.5f * v2 * (1.f + erff(v2 * 0.70710678118654752f));
        r.w = 0.5f * v3 * (1.f + erff(v3 * 0.70710678118654752f));
        *(float4*)(op + mt * 16 + 4 * g) = r;
    }
}

// ---------------------------------------------------------------------------
extern "C" void kernel_launch(void* const* d_in, const int* in_sizes, int n_in,
                              void* d_out, int out_size, void* d_ws, size_t ws_size,
                              hipStream_t stream)
{
    const float* x  = (const float*)d_in[0];
    const float* qw = (const float*)d_in[1];
    const float* kw = (const float*)d_in[2];
    const float* vw = (const float*)d_in[3];
    float* out = (float*)d_out;

    // workspace layout (f16 elements)
    _Float16* wt  = (_Float16*)d_ws;            // [3][H][VD][D]   =  786432
    _Float16* xhp = wt  + 786432;               // [B*N][D]        = 2097152
    _Float16* qsp = xhp + 2097152;              // [BH][N][VD]     = 2097152
    _Float16* kbp = qsp + 2097152;
    _Float16* vtp = kbp + 2097152;

    hipLaunchKernelGGL(prep_kernel, dim3(192 + 1024), dim3(256), 0, stream,
                       x, qw, kw, vw, wt, xhp);
    hipLaunchKernelGGL(qkv_proj_kernel, dim3(512), dim3(256), 0, stream,
                       xhp, wt, qsp, kbp, vtp);
    hipLaunchKernelGGL(attn_kernel, dim3(512), dim3(256), 0, stream,
                       qsp, kbp, vtp, out);
}

// Round 4
// 64.974 us; speedup vs baseline: 2.8021x; 1.0535x over previous
//
#include <hip/hip_runtime.h>
#include <hip/hip_bf16.h>
#include <math.h>

// Problem constants
#define BB 2
#define NN 2048
#define DD 512
#define HH 8
#define VD 64
#define SPLIT 2
#define KVH (NN / SPLIT)      // 1024 kv per split block
#define NITER (KVH / 64)      // 16

typedef _Float16 half8 __attribute__((ext_vector_type(8)));
typedef _Float16 half4 __attribute__((ext_vector_type(4)));
typedef float f32x4 __attribute__((ext_vector_type(4)));

#define GLDS16(gp, lp) __builtin_amdgcn_global_load_lds( \
    (const __attribute__((address_space(1))) void*)(gp), \
    (__attribute__((address_space(3))) void*)(lp), 16, 0, 0)

__device__ __forceinline__ float fexp2(float x) {
#if __has_builtin(__builtin_amdgcn_exp2f)
    return __builtin_amdgcn_exp2f(x);
#else
    return exp2f(x);
#endif
}

// Stage 8 rows x 64 f16 cols (1KB) from global into LDS linear, source
// pre-swizzled so a swizzled read sees logical layout (T2 both-sides).
__device__ __forceinline__ void stage8(const _Float16* gsrc, size_t ldg, int r0,
                                       _Float16* lbase, int lane) {
    int r8 = lane >> 3;
    int ce = ((lane & 7) ^ r8) << 3;
    const _Float16* g = gsrc + (size_t)(r0 + r8) * ldg + ce;
    GLDS16(g, lbase);
}

// Swizzled half8 read: logical (row, col-byte cb) of a [*][128B] tile.
__device__ __forceinline__ half8 frag_ld(const _Float16* tile, int row, int cb) {
    int off = row * 128 + (cb ^ ((row & 7) << 4));
    return *(const half8*)((const char*)tile + off);
}

__device__ __forceinline__ float gelu_exact(float v) {
    return 0.5f * v * (1.f + erff(v * 0.70710678118654752f));
}

// ---------------------------------------------------------------------------
// prep: blocks 0..191: weight transpose fp32 [H][D][VD] -> f16 Wt[3][H][VD][D]
//       blocks 192..1215: X fp32 -> f16 cast
// ---------------------------------------------------------------------------
__global__ __launch_bounds__(256) void prep_kernel(
    const float* __restrict__ x,
    const float* __restrict__ qw, const float* __restrict__ kw,
    const float* __restrict__ vw,
    _Float16* __restrict__ wt, _Float16* __restrict__ xh)
{
    __shared__ float ls[64][65];
    const int t = threadIdx.x;
    const int bid = blockIdx.x;
    if (bid < 192) {
        const int kc = bid & 7, h = (bid >> 3) & 7, ty = bid >> 6;
        const float* src = (ty == 0) ? qw : (ty == 1) ? kw : vw;
#pragma unroll
        for (int j = 0; j < 4; ++j) {
            int idx = t + 256 * j;
            int k = idx >> 4, o4 = idx & 15;
            float4 v = *(const float4*)(src + ((size_t)(h * DD + kc * 64 + k) * VD + o4 * 4));
            ls[k][o4 * 4 + 0] = v.x; ls[k][o4 * 4 + 1] = v.y;
            ls[k][o4 * 4 + 2] = v.z; ls[k][o4 * 4 + 3] = v.w;
        }
        __syncthreads();
#pragma unroll
        for (int j = 0; j < 4; ++j) {
            int idx = t + 256 * j;
            int o = idx >> 4, k4 = idx & 15;
            half4 hv;
#pragma unroll
            for (int i = 0; i < 4; ++i) hv[i] = (_Float16)ls[k4 * 4 + i][o];
            *(half4*)(wt + ((size_t)(ty * HH + h) * VD + o) * DD + kc * 64 + k4 * 4) = hv;
        }
    } else {
        size_t idx = ((size_t)(bid - 192) * 256 + t) * 8;
        float4 a = *(const float4*)(x + idx);
        float4 b = *(const float4*)(x + idx + 4);
        half8 hv;
        hv[0] = (_Float16)a.x; hv[1] = (_Float16)a.y;
        hv[2] = (_Float16)a.z; hv[3] = (_Float16)a.w;
        hv[4] = (_Float16)b.x; hv[5] = (_Float16)b.y;
        hv[6] = (_Float16)b.z; hv[7] = (_Float16)b.w;
        *(half8*)(xh + idx) = hv;
    }
}

// ---------------------------------------------------------------------------
// QKV projection (Q pre-scale folds softmax 1/8 AND log2(e)).
// ---------------------------------------------------------------------------
__global__ __launch_bounds__(256) void qkv_proj_kernel(
    const _Float16* __restrict__ xh,
    const _Float16* __restrict__ wt,
    _Float16* __restrict__ qsp,
    _Float16* __restrict__ kbp,
    _Float16* __restrict__ vtp)
{
    __shared__ __align__(16) _Float16 xls[2][4096];
    __shared__ __align__(16) _Float16 wls[2][12288];
    const int t = threadIdx.x;
    const int wave = t >> 6, lane = t & 63;
    const int lq = lane & 15, g = lane >> 4;
    const int bid = blockIdx.x;
    const int h = bid & 7;
    const int m0 = (bid >> 3) * 64;
    const int rbase = 32 * (wave >> 1);
    const int cbase = 96 * (wave & 1);

    f32x4 acc[2][6];
#pragma unroll
    for (int a = 0; a < 2; ++a)
#pragma unroll
        for (int c = 0; c < 6; ++c) acc[a][c] = (f32x4){0.f, 0.f, 0.f, 0.f};

    auto stage = [&](int buf, int ks) {
#pragma unroll
        for (int j = 0; j < 2; ++j) {
            int i = wave * 2 + j;
            stage8(xh + (size_t)m0 * DD + ks * 64, DD, i * 8, &xls[buf][i * 512], lane);
        }
#pragma unroll
        for (int j = 0; j < 6; ++j) {
            int i = wave * 6 + j;
            int ty = i >> 3;
            int ol = (i & 7) * 8;
            stage8(wt + ((size_t)(ty * HH + h) * VD + ol) * DD + ks * 64, DD, 0,
                   &wls[buf][i * 512], lane);
        }
    };

    stage(0, 0);
    __syncthreads();
    int buf = 0;
    for (int ks = 0; ks < 8; ++ks) {
        if (ks < 7) stage(buf ^ 1, ks + 1);
        half8 af[2][2];
#pragma unroll
        for (int amt = 0; amt < 2; ++amt) {
            af[amt][0] = frag_ld(xls[buf], rbase + amt * 16 + lq, 16 * g);
            af[amt][1] = frag_ld(xls[buf], rbase + amt * 16 + lq, 64 + 16 * g);
        }
#pragma unroll
        for (int ct = 0; ct < 6; ++ct) {
            int wr = cbase + ct * 16 + lq;
            half8 bf0 = frag_ld(wls[buf], wr, 16 * g);
            half8 bf1 = frag_ld(wls[buf], wr, 64 + 16 * g);
#pragma unroll
            for (int amt = 0; amt < 2; ++amt) {
                acc[amt][ct] = __builtin_amdgcn_mfma_f32_16x16x32_f16(af[amt][0], bf0, acc[amt][ct], 0, 0, 0);
                acc[amt][ct] = __builtin_amdgcn_mfma_f32_16x16x32_f16(af[amt][1], bf1, acc[amt][ct], 0, 0, 0);
            }
        }
        __syncthreads();
        buf ^= 1;
    }

#pragma unroll
    for (int ct = 0; ct < 6; ++ct) {
        int gcol = cbase + ct * 16 + lq;
        int ty = gcol >> 6, o = gcol & 63;
#pragma unroll
        for (int amt = 0; amt < 2; ++amt) {
#pragma unroll
            for (int i = 0; i < 4; ++i) {
                int ng = m0 + rbase + amt * 16 + 4 * g + i;
                int b = ng >> 11, nb = ng & (NN - 1);
                size_t bh = (size_t)(b * HH + h);
                float v = acc[amt][ct][i];
                // fold softmax scale (1/8) AND log2(e) into Q so attn uses exp2
                if (ty == 0)      qsp[(bh * NN + nb) * VD + o] = (_Float16)(v * 0.18033688011112042f);
                else if (ty == 1) kbp[(bh * NN + nb) * VD + o] = (_Float16)v;
                else              vtp[(bh * VD + o) * NN + nb] = (_Float16)v;
            }
        }
    }
}

// ---------------------------------------------------------------------------
// Flash attention, split-kv. Grid 1024 = 8 XCD x 4 (s,bh)-pairs x 32 q-tiles.
// Block 256 (4 waves), LDS = 40960B -> 4 blocks/CU (16 waves/CU).
// Outputs unnormalized partial O (f32) + per-row (m, l) in log2 domain.
// ---------------------------------------------------------------------------
__global__ __launch_bounds__(256, 4) void attn_kernel(
    const _Float16* __restrict__ qs,   // [BH][N][VD], scaled log2e/8
    const _Float16* __restrict__ kb,   // [BH][N][VD]
    const _Float16* __restrict__ vt,   // [BH][VD][N]
    float* __restrict__ opart,         // [SPLIT][BH][N][VD] f32
    float2* __restrict__ ml)           // [SPLIT][BH][N] (m, l)
{
    __shared__ __align__(16) _Float16 kls[2][4096];   // [kv=64][d=64] swizzled
    __shared__ __align__(16) _Float16 vls[2][4096];   // [d=64][kv=64] swizzled
    __shared__ __align__(16) _Float16 pls[4][1024];   // wave-private P[16][64] swizzled
    const int t = threadIdx.x;
    const int wave = t >> 6, lane = t & 63;
    const int lq = lane & 15, g = lane >> 4;
    const int bid = blockIdx.x;
    const int xcd = bid & 7;
    const int idx = bid >> 3;
    const int sbh = (idx >> 5) * 8 + xcd;     // 0..31, same (s,bh) stays on one XCD
    const int s = sbh >> 4, bh = sbh & 15;
    const int qt = idx & 31;
    const int qrow = qt * 64 + wave * 16 + lq;
    const int kvs = s * KVH;

    const _Float16* qp = qs + ((size_t)bh * NN + qrow) * VD + 8 * g;
    half8 qf0 = *(const half8*)qp;
    half8 qf1 = *(const half8*)(qp + 32);

    // staging pointers: lane-resolved source (pre-swizzled), constant strides
    const int r8 = lane >> 3;
    const int ce = ((lane & 7) ^ r8) << 3;
    const _Float16* kg = kb + (size_t)bh * NN * VD + (size_t)(kvs + wave * 16 + r8) * VD + ce;
    const _Float16* vg = vt + (size_t)bh * VD * NN + (size_t)(wave * 16 + r8) * NN + kvs + ce;
    char* pb = (char*)&pls[wave][0];

    f32x4 oacc[4];
#pragma unroll
    for (int mt = 0; mt < 4; ++mt) oacc[mt] = (f32x4){0.f, 0.f, 0.f, 0.f};
    float mrun = -INFINITY, lsum = 0.f;

    auto stagekv = [&](int buf, int itn) {
        const _Float16* kp = kg + (size_t)itn * 4096;   // 64 rows x 64 halves
        GLDS16(kp, &kls[buf][wave * 1024]);
        GLDS16(kp + 8 * VD, &kls[buf][wave * 1024 + 512]);
        const _Float16* vp = vg + itn * 64;             // advance 64 kv cols
        GLDS16(vp, &vls[buf][wave * 1024]);
        GLDS16(vp + 8 * NN, &vls[buf][wave * 1024 + 512]);
    };

    stagekv(0, 0);
    __syncthreads();

#define AT_BODY(BUF, ITN)                                                        \
    {                                                                            \
        if ((ITN) < NITER - 1) stagekv((BUF) ^ 1, (ITN) + 1);                    \
        f32x4 sv[4];                                                             \
        __builtin_amdgcn_s_setprio(1);                                           \
        _Pragma("unroll") for (int mt = 0; mt < 4; ++mt) {                       \
            half8 k0 = frag_ld(kls[BUF], mt * 16 + lq, 16 * g);                  \
            half8 k1 = frag_ld(kls[BUF], mt * 16 + lq, 64 + 16 * g);             \
            sv[mt] = (f32x4){0.f, 0.f, 0.f, 0.f};                                \
            sv[mt] = __builtin_amdgcn_mfma_f32_16x16x32_f16(k0, qf0, sv[mt], 0, 0, 0); \
            sv[mt] = __builtin_amdgcn_mfma_f32_16x16x32_f16(k1, qf1, sv[mt], 0, 0, 0); \
        }                                                                        \
        __builtin_amdgcn_s_setprio(0);                                           \
        float tm0 = fmaxf(fmaxf(sv[0][0], sv[0][1]), fmaxf(sv[0][2], sv[0][3])); \
        float tm1 = fmaxf(fmaxf(sv[1][0], sv[1][1]), fmaxf(sv[1][2], sv[1][3])); \
        float tm2 = fmaxf(fmaxf(sv[2][0], sv[2][1]), fmaxf(sv[2][2], sv[2][3])); \
        float tm3 = fmaxf(fmaxf(sv[3][0], sv[3][1]), fmaxf(sv[3][2], sv[3][3])); \
        float tmax = fmaxf(fmaxf(tm0, tm1), fmaxf(tm2, tm3));                    \
        tmax = fmaxf(tmax, __shfl_xor(tmax, 16, 64));                            \
        tmax = fmaxf(tmax, __shfl_xor(tmax, 32, 64));                            \
        if (__any(tmax > mrun + 8.f)) {                                          \
            float mnew = fmaxf(mrun, tmax);                                      \
            float corr = fexp2(mrun - mnew);                                     \
            lsum *= corr;                                                        \
            _Pragma("unroll") for (int mt = 0; mt < 4; ++mt)                     \
                _Pragma("unroll") for (int i = 0; i < 4; ++i) oacc[mt][i] *= corr; \
            mrun = mnew;                                                         \
        }                                                                        \
        float psum = 0.f;                                                        \
        _Pragma("unroll") for (int mt = 0; mt < 4; ++mt) {                       \
            half4 pv;                                                            \
            _Pragma("unroll") for (int i = 0; i < 4; ++i) {                      \
                float p = fexp2(sv[mt][i] - mrun);                               \
                psum += p;                                                       \
                pv[i] = (_Float16)p;                                             \
            }                                                                    \
            *(half4*)(pb + lq * 128 + ((mt * 32 + 8 * g) ^ ((lq & 7) << 4))) = pv; \
        }                                                                        \
        psum += __shfl_xor(psum, 16, 64);                                        \
        psum += __shfl_xor(psum, 32, 64);                                        \
        lsum += psum;                                                            \
        asm volatile("s_waitcnt lgkmcnt(0)" ::: "memory");                       \
        __builtin_amdgcn_s_setprio(1);                                           \
        _Pragma("unroll") for (int kc = 0; kc < 2; ++kc) {                       \
            half8 pf = *(const half8*)(pb + lq * 128 + ((kc * 64 + 16 * g) ^ ((lq & 7) << 4))); \
            _Pragma("unroll") for (int mt = 0; mt < 4; ++mt) {                   \
                half8 vf = frag_ld(vls[BUF], mt * 16 + lq, kc * 64 + 16 * g);    \
                oacc[mt] = __builtin_amdgcn_mfma_f32_16x16x32_f16(vf, pf, oacc[mt], 0, 0, 0); \
            }                                                                    \
        }                                                                        \
        __builtin_amdgcn_s_setprio(0);                                           \
        __syncthreads();                                                         \
    }

    for (int it = 0; it < NITER; it += 2) {
        AT_BODY(0, it);
        AT_BODY(1, it + 1);
    }
#undef AT_BODY

    // store unnormalized partial O + (m, l)
    float* op = opart + (((size_t)s * (BB * HH) + bh) * NN + qrow) * VD;
#pragma unroll
    for (int mt = 0; mt < 4; ++mt) {
        float4 r;
        r.x = oacc[mt][0]; r.y = oacc[mt][1]; r.z = oacc[mt][2]; r.w = oacc[mt][3];
        *(float4*)(op + mt * 16 + 4 * g) = r;
    }
    if (g == 0) {
        float2 v; v.x = mrun; v.y = lsum;
        ml[((size_t)s * (BB * HH) + bh) * NN + qrow] = v;
    }
}

// ---------------------------------------------------------------------------
// Combine split-kv partials + GELU. 32768 rows x 64 d. Block 256 = 32 rows.
// ---------------------------------------------------------------------------
__global__ __launch_bounds__(256) void combine_kernel(
    const float* __restrict__ opart, const float2* __restrict__ ml,
    float* __restrict__ out)
{
    const int t = threadIdx.x;
    const int r = blockIdx.x * 32 + (t >> 3);   // bh*2048 + n
    const int d0 = (t & 7) * 8;
    float2 a = ml[r];
    float2 b = ml[BB * HH * NN + r];
    float M = fmaxf(a.x, b.x);
    float c0 = fexp2(a.x - M), c1 = fexp2(b.x - M);
    float inv = 1.f / (c0 * a.y + c1 * b.y);
    const float* p0 = opart + (size_t)r * VD + d0;
    const float* p1 = p0 + (size_t)(BB * HH) * NN * VD;
    float4 x0 = *(const float4*)p0;
    float4 x1 = *(const float4*)(p0 + 4);
    float4 y0 = *(const float4*)p1;
    float4 y1 = *(const float4*)(p1 + 4);
    const int bh = r >> 11, n = r & (NN - 1);
    float* op = out + ((size_t)(bh >> 3) * NN + n) * (HH * VD) + (bh & 7) * VD + d0;
    float4 o0, o1;
    o0.x = gelu_exact((c0 * x0.x + c1 * y0.x) * inv);
    o0.y = gelu_exact((c0 * x0.y + c1 * y0.y) * inv);
    o0.z = gelu_exact((c0 * x0.z + c1 * y0.z) * inv);
    o0.w = gelu_exact((c0 * x0.w + c1 * y0.w) * inv);
    o1.x = gelu_exact((c0 * x1.x + c1 * y1.x) * inv);
    o1.y = gelu_exact((c0 * x1.y + c1 * y1.y) * inv);
    o1.z = gelu_exact((c0 * x1.z + c1 * y1.z) * inv);
    o1.w = gelu_exact((c0 * x1.w + c1 * y1.w) * inv);
    *(float4*)op = o0;
    *(float4*)(op + 4) = o1;
}

// ---------------------------------------------------------------------------
extern "C" void kernel_launch(void* const* d_in, const int* in_sizes, int n_in,
                              void* d_out, int out_size, void* d_ws, size_t ws_size,
                              hipStream_t stream)
{
    const float* x  = (const float*)d_in[0];
    const float* qw = (const float*)d_in[1];
    const float* kw = (const float*)d_in[2];
    const float* vw = (const float*)d_in[3];
    float* out = (float*)d_out;

    // workspace layout
    _Float16* wt  = (_Float16*)d_ws;            // [3][H][VD][D]   =  786432 halves
    _Float16* xhp = wt  + 786432;               // [B*N][D]        = 2097152
    _Float16* qsp = xhp + 2097152;
    _Float16* kbp = qsp + 2097152;
    _Float16* vtp = kbp + 2097152;
    float*  opart = (float*)(vtp + 2097152);    // [2][16][2048][64] f32 = 16MB
    float2* mlp   = (float2*)(opart + (size_t)SPLIT * BB * HH * NN * VD);  // 512KB

    hipLaunchKernelGGL(prep_kernel, dim3(192 + 1024), dim3(256), 0, stream,
                       x, qw, kw, vw, wt, xhp);
    hipLaunchKernelGGL(qkv_proj_kernel, dim3(512), dim3(256), 0, stream,
                       xhp, wt, qsp, kbp, vtp);
    hipLaunchKernelGGL(attn_kernel, dim3(1024), dim3(256), 0, stream,
                       qsp, kbp, vtp, opart, mlp);
    hipLaunchKernelGGL(combine_kernel, dim3(BB * HH * NN / 32), dim3(256), 0, stream,
                       opart, mlp, out);
}

// Round 5
// 62.664 us; speedup vs baseline: 2.9054x; 1.0368x over previous
//
#include <hip/hip_runtime.h>
#include <hip/hip_bf16.h>
#include <math.h>

// Problem constants
#define BB 2
#define NN 2048
#define DD 512
#define HH 8
#define VD 64
#define SPLIT 2
#define KVH (NN / SPLIT)      // 1024 kv per split block
#define NITER (KVH / 64)      // 16

typedef _Float16 half8 __attribute__((ext_vector_type(8)));
typedef _Float16 half4 __attribute__((ext_vector_type(4)));
typedef float f32x4 __attribute__((ext_vector_type(4)));

#define GLDS16(gp, lp) __builtin_amdgcn_global_load_lds( \
    (const __attribute__((address_space(1))) void*)(gp), \
    (__attribute__((address_space(3))) void*)(lp), 16, 0, 0)

__device__ __forceinline__ float fexp2(float x) {
#if __has_builtin(__builtin_amdgcn_exp2f)
    return __builtin_amdgcn_exp2f(x);
#else
    return exp2f(x);
#endif
}

// Stage 8 rows x 64 f16 cols (1KB) from global into LDS linear, source
// pre-swizzled so a swizzled read sees logical layout (T2 both-sides).
__device__ __forceinline__ void stage8(const _Float16* gsrc, size_t ldg, int r0,
                                       _Float16* lbase, int lane) {
    int r8 = lane >> 3;
    int ce = ((lane & 7) ^ r8) << 3;
    const _Float16* g = gsrc + (size_t)(r0 + r8) * ldg + ce;
    GLDS16(g, lbase);
}

// Swizzled half8 read: logical (row, col-byte cb) of a [*][128B] tile.
__device__ __forceinline__ half8 frag_ld(const _Float16* tile, int row, int cb) {
    int off = row * 128 + (cb ^ ((row & 7) << 4));
    return *(const half8*)((const char*)tile + off);
}

__device__ __forceinline__ float gelu_exact(float v) {
    return 0.5f * v * (1.f + erff(v * 0.70710678118654752f));
}

// ---------------------------------------------------------------------------
// prep: blocks 0..191: weight transpose fp32 [H][D][VD] -> f16 Wt[3][H][VD][D]
//       blocks 192..1215: X fp32 -> f16 cast
// ---------------------------------------------------------------------------
__global__ __launch_bounds__(256) void prep_kernel(
    const float* __restrict__ x,
    const float* __restrict__ qw, const float* __restrict__ kw,
    const float* __restrict__ vw,
    _Float16* __restrict__ wt, _Float16* __restrict__ xh)
{
    __shared__ float ls[64][65];
    const int t = threadIdx.x;
    const int bid = blockIdx.x;
    if (bid < 192) {
        const int kc = bid & 7, h = (bid >> 3) & 7, ty = bid >> 6;
        const float* src = (ty == 0) ? qw : (ty == 1) ? kw : vw;
#pragma unroll
        for (int j = 0; j < 4; ++j) {
            int idx = t + 256 * j;
            int k = idx >> 4, o4 = idx & 15;
            float4 v = *(const float4*)(src + ((size_t)(h * DD + kc * 64 + k) * VD + o4 * 4));
            ls[k][o4 * 4 + 0] = v.x; ls[k][o4 * 4 + 1] = v.y;
            ls[k][o4 * 4 + 2] = v.z; ls[k][o4 * 4 + 3] = v.w;
        }
        __syncthreads();
#pragma unroll
        for (int j = 0; j < 4; ++j) {
            int idx = t + 256 * j;
            int o = idx >> 4, k4 = idx & 15;
            half4 hv;
#pragma unroll
            for (int i = 0; i < 4; ++i) hv[i] = (_Float16)ls[k4 * 4 + i][o];
            *(half4*)(wt + ((size_t)(ty * HH + h) * VD + o) * DD + kc * 64 + k4 * 4) = hv;
        }
    } else {
        size_t idx = ((size_t)(bid - 192) * 256 + t) * 8;
        float4 a = *(const float4*)(x + idx);
        float4 b = *(const float4*)(x + idx + 4);
        half8 hv;
        hv[0] = (_Float16)a.x; hv[1] = (_Float16)a.y;
        hv[2] = (_Float16)a.z; hv[3] = (_Float16)a.w;
        hv[4] = (_Float16)b.x; hv[5] = (_Float16)b.y;
        hv[6] = (_Float16)b.z; hv[7] = (_Float16)b.w;
        *(half8*)(xh + idx) = hv;
    }
}

// ---------------------------------------------------------------------------
// QKV projection (Q pre-scale folds softmax 1/8 AND log2(e)).
// ---------------------------------------------------------------------------
__global__ __launch_bounds__(256) void qkv_proj_kernel(
    const _Float16* __restrict__ xh,
    const _Float16* __restrict__ wt,
    _Float16* __restrict__ qsp,
    _Float16* __restrict__ kbp,
    _Float16* __restrict__ vtp)
{
    __shared__ __align__(16) _Float16 xls[2][4096];
    __shared__ __align__(16) _Float16 wls[2][12288];
    const int t = threadIdx.x;
    const int wave = t >> 6, lane = t & 63;
    const int lq = lane & 15, g = lane >> 4;
    const int bid = blockIdx.x;
    const int h = bid & 7;
    const int m0 = (bid >> 3) * 64;
    const int rbase = 32 * (wave >> 1);
    const int cbase = 96 * (wave & 1);

    f32x4 acc[2][6];
#pragma unroll
    for (int a = 0; a < 2; ++a)
#pragma unroll
        for (int c = 0; c < 6; ++c) acc[a][c] = (f32x4){0.f, 0.f, 0.f, 0.f};

    auto stage = [&](int buf, int ks) {
#pragma unroll
        for (int j = 0; j < 2; ++j) {
            int i = wave * 2 + j;
            stage8(xh + (size_t)m0 * DD + ks * 64, DD, i * 8, &xls[buf][i * 512], lane);
        }
#pragma unroll
        for (int j = 0; j < 6; ++j) {
            int i = wave * 6 + j;
            int ty = i >> 3;
            int ol = (i & 7) * 8;
            stage8(wt + ((size_t)(ty * HH + h) * VD + ol) * DD + ks * 64, DD, 0,
                   &wls[buf][i * 512], lane);
        }
    };

    stage(0, 0);
    __syncthreads();
    int buf = 0;
    for (int ks = 0; ks < 8; ++ks) {
        if (ks < 7) stage(buf ^ 1, ks + 1);
        half8 af[2][2];
#pragma unroll
        for (int amt = 0; amt < 2; ++amt) {
            af[amt][0] = frag_ld(xls[buf], rbase + amt * 16 + lq, 16 * g);
            af[amt][1] = frag_ld(xls[buf], rbase + amt * 16 + lq, 64 + 16 * g);
        }
#pragma unroll
        for (int ct = 0; ct < 6; ++ct) {
            int wr = cbase + ct * 16 + lq;
            half8 bf0 = frag_ld(wls[buf], wr, 16 * g);
            half8 bf1 = frag_ld(wls[buf], wr, 64 + 16 * g);
#pragma unroll
            for (int amt = 0; amt < 2; ++amt) {
                acc[amt][ct] = __builtin_amdgcn_mfma_f32_16x16x32_f16(af[amt][0], bf0, acc[amt][ct], 0, 0, 0);
                acc[amt][ct] = __builtin_amdgcn_mfma_f32_16x16x32_f16(af[amt][1], bf1, acc[amt][ct], 0, 0, 0);
            }
        }
        __syncthreads();
        buf ^= 1;
    }

#pragma unroll
    for (int ct = 0; ct < 6; ++ct) {
        int gcol = cbase + ct * 16 + lq;
        int ty = gcol >> 6, o = gcol & 63;
#pragma unroll
        for (int amt = 0; amt < 2; ++amt) {
#pragma unroll
            for (int i = 0; i < 4; ++i) {
                int ng = m0 + rbase + amt * 16 + 4 * g + i;
                int b = ng >> 11, nb = ng & (NN - 1);
                size_t bh = (size_t)(b * HH + h);
                float v = acc[amt][ct][i];
                if (ty == 0)      qsp[(bh * NN + nb) * VD + o] = (_Float16)(v * 0.18033688011112042f);
                else if (ty == 1) kbp[(bh * NN + nb) * VD + o] = (_Float16)v;
                else              vtp[(bh * VD + o) * NN + nb] = (_Float16)v;
            }
        }
    }
}

// ---------------------------------------------------------------------------
// Flash attention, split-kv, 32 q-columns per wave (128 q rows per block).
// Grid 512 = 8 XCD x 4 (s,bh) x 16 q-tiles. LDS 48KB.
// Per wave-iter: 32 MFMA on the same K/V fragments (2 Q-frag sets) ->
// FLOP per LDS byte ~2x round-4. lsum kept lane-partial (no per-iter shfl).
// ---------------------------------------------------------------------------
__global__ __launch_bounds__(256, 2) void attn_kernel(
    const _Float16* __restrict__ qs,   // [BH][N][VD], scaled log2e/8
    const _Float16* __restrict__ kb,   // [BH][N][VD]
    const _Float16* __restrict__ vt,   // [BH][VD][N]
    float* __restrict__ opart,         // [SPLIT][BH][N][VD] f32
    float2* __restrict__ ml)           // [SPLIT][BH][N] (m, l)
{
    __shared__ __align__(16) _Float16 kls[2][4096];   // [kv=64][d=64] swizzled
    __shared__ __align__(16) _Float16 vls[2][4096];   // [d=64][kv=64] swizzled
    __shared__ __align__(16) _Float16 pls[4][2048];   // per-wave P[32 q][64 kv] swizzled
    const int t = threadIdx.x;
    const int wave = t >> 6, lane = t & 63;
    const int lq = lane & 15, g = lane >> 4;
    const int bid = blockIdx.x;
    const int xcd = bid & 7;
    const int idx = bid >> 3;                 // 0..63
    const int sbh = (idx >> 4) * 8 + xcd;     // 0..31, (s,bh) pinned to one XCD
    const int s = sbh >> 4, bh = sbh & 15;
    const int qt = idx & 15;                  // 16 q-tiles of 128 rows
    const int qbase = qt * 128 + wave * 32;
    const int kvs = s * KVH;

    // Q fragments: 2 q-halves x 2 k-slices
    half8 qf[2][2];
#pragma unroll
    for (int qh = 0; qh < 2; ++qh) {
        const _Float16* qp = qs + ((size_t)bh * NN + qbase + qh * 16 + lq) * VD + 8 * g;
        qf[qh][0] = *(const half8*)qp;
        qf[qh][1] = *(const half8*)(qp + 32);
    }

    // staging pointers: lane-resolved pre-swizzled source, constant strides
    const int r8 = lane >> 3;
    const int ce = ((lane & 7) ^ r8) << 3;
    const _Float16* kg = kb + (size_t)bh * NN * VD + (size_t)(kvs + wave * 16 + r8) * VD + ce;
    const _Float16* vg = vt + (size_t)bh * VD * NN + (size_t)(wave * 16 + r8) * NN + kvs + ce;
    char* pb = (char*)&pls[wave][0];

    f32x4 oacc[2][4];
#pragma unroll
    for (int qh = 0; qh < 2; ++qh)
#pragma unroll
        for (int mt = 0; mt < 4; ++mt) oacc[qh][mt] = (f32x4){0.f, 0.f, 0.f, 0.f};
    float mrun[2] = {-INFINITY, -INFINITY};
    float lsum[2] = {0.f, 0.f};               // lane-partial; reduced once at end

    auto stagekv = [&](int buf, int itn) {
        const _Float16* kp = kg + (size_t)itn * 4096;
        GLDS16(kp, &kls[buf][wave * 1024]);
        GLDS16(kp + 8 * VD, &kls[buf][wave * 1024 + 512]);
        const _Float16* vp = vg + itn * 64;
        GLDS16(vp, &vls[buf][wave * 1024]);
        GLDS16(vp + 8 * NN, &vls[buf][wave * 1024 + 512]);
    };

    stagekv(0, 0);
    __syncthreads();

#define AT_BODY(BUF, ITN)                                                        \
    {                                                                            \
        if ((ITN) < NITER - 1) stagekv((BUF) ^ 1, (ITN) + 1);                    \
        f32x4 sv[2][4];                                                          \
        __builtin_amdgcn_s_setprio(1);                                           \
        _Pragma("unroll") for (int mt = 0; mt < 4; ++mt) {                       \
            half8 k0 = frag_ld(kls[BUF], mt * 16 + lq, 16 * g);                  \
            half8 k1 = frag_ld(kls[BUF], mt * 16 + lq, 64 + 16 * g);             \
            _Pragma("unroll") for (int qh = 0; qh < 2; ++qh) {                   \
                sv[qh][mt] = (f32x4){0.f, 0.f, 0.f, 0.f};                        \
                sv[qh][mt] = __builtin_amdgcn_mfma_f32_16x16x32_f16(k0, qf[qh][0], sv[qh][mt], 0, 0, 0); \
                sv[qh][mt] = __builtin_amdgcn_mfma_f32_16x16x32_f16(k1, qf[qh][1], sv[qh][mt], 0, 0, 0); \
            }                                                                    \
        }                                                                        \
        __builtin_amdgcn_s_setprio(0);                                           \
        _Pragma("unroll") for (int qh = 0; qh < 2; ++qh) {                       \
            float a0 = fmaxf(fmaxf(sv[qh][0][0], sv[qh][0][1]), fmaxf(sv[qh][0][2], sv[qh][0][3])); \
            float a1 = fmaxf(fmaxf(sv[qh][1][0], sv[qh][1][1]), fmaxf(sv[qh][1][2], sv[qh][1][3])); \
            float a2 = fmaxf(fmaxf(sv[qh][2][0], sv[qh][2][1]), fmaxf(sv[qh][2][2], sv[qh][2][3])); \
            float a3 = fmaxf(fmaxf(sv[qh][3][0], sv[qh][3][1]), fmaxf(sv[qh][3][2], sv[qh][3][3])); \
            float tmax = fmaxf(fmaxf(a0, a1), fmaxf(a2, a3));                    \
            tmax = fmaxf(tmax, __shfl_xor(tmax, 16, 64));                        \
            tmax = fmaxf(tmax, __shfl_xor(tmax, 32, 64));                        \
            if (__any(tmax > mrun[qh] + 8.f)) {                                  \
                float mnew = fmaxf(mrun[qh], tmax);                              \
                float corr = fexp2(mrun[qh] - mnew);                             \
                lsum[qh] *= corr;                                                \
                _Pragma("unroll") for (int mt = 0; mt < 4; ++mt)                 \
                    _Pragma("unroll") for (int i = 0; i < 4; ++i) oacc[qh][mt][i] *= corr; \
                mrun[qh] = mnew;                                                 \
            }                                                                    \
            _Pragma("unroll") for (int mt = 0; mt < 4; ++mt) {                   \
                half4 pv;                                                        \
                _Pragma("unroll") for (int i = 0; i < 4; ++i) {                  \
                    float p = fexp2(sv[qh][mt][i] - mrun[qh]);                   \
                    lsum[qh] += p;                                               \
                    pv[i] = (_Float16)p;                                         \
                }                                                                \
                *(half4*)(pb + (qh * 16 + lq) * 128 + ((mt * 32 + 8 * g) ^ ((lq & 7) << 4))) = pv; \
            }                                                                    \
        }                                                                        \
        asm volatile("s_waitcnt lgkmcnt(0)" ::: "memory");                       \
        __builtin_amdgcn_s_setprio(1);                                           \
        _Pragma("unroll") for (int kc = 0; kc < 2; ++kc) {                       \
            half8 pf0 = *(const half8*)(pb + lq * 128 + ((kc * 64 + 16 * g) ^ ((lq & 7) << 4))); \
            half8 pf1 = *(const half8*)(pb + (16 + lq) * 128 + ((kc * 64 + 16 * g) ^ ((lq & 7) << 4))); \
            _Pragma("unroll") for (int mt = 0; mt < 4; ++mt) {                   \
                half8 vf = frag_ld(vls[BUF], mt * 16 + lq, kc * 64 + 16 * g);    \
                oacc[0][mt] = __builtin_amdgcn_mfma_f32_16x16x32_f16(vf, pf0, oacc[0][mt], 0, 0, 0); \
                oacc[1][mt] = __builtin_amdgcn_mfma_f32_16x16x32_f16(vf, pf1, oacc[1][mt], 0, 0, 0); \
            }                                                                    \
        }                                                                        \
        __builtin_amdgcn_s_setprio(0);                                           \
        __syncthreads();                                                         \
    }

    for (int it = 0; it < NITER; it += 2) {
        AT_BODY(0, it);
        AT_BODY(1, it + 1);
    }
#undef AT_BODY

    // final lsum reduction over g-groups, then store partial O + (m, l)
#pragma unroll
    for (int qh = 0; qh < 2; ++qh) {
        float l = lsum[qh];
        l += __shfl_xor(l, 16, 64);
        l += __shfl_xor(l, 32, 64);
        float* op = opart + (((size_t)s * (BB * HH) + bh) * NN + qbase + qh * 16 + lq) * VD;
#pragma unroll
        for (int mt = 0; mt < 4; ++mt) {
            float4 r;
            r.x = oacc[qh][mt][0]; r.y = oacc[qh][mt][1];
            r.z = oacc[qh][mt][2]; r.w = oacc[qh][mt][3];
            *(float4*)(op + mt * 16 + 4 * g) = r;
        }
        if (g == 0) {
            float2 v; v.x = mrun[qh]; v.y = l;
            ml[((size_t)s * (BB * HH) + bh) * NN + qbase + qh * 16 + lq] = v;
        }
    }
}

// ---------------------------------------------------------------------------
// Combine split-kv partials + GELU. 32768 rows x 64 d. Block 256 = 32 rows.
// ---------------------------------------------------------------------------
__global__ __launch_bounds__(256) void combine_kernel(
    const float* __restrict__ opart, const float2* __restrict__ ml,
    float* __restrict__ out)
{
    const int t = threadIdx.x;
    const int r = blockIdx.x * 32 + (t >> 3);   // bh*2048 + n
    const int d0 = (t & 7) * 8;
    float2 a = ml[r];
    float2 b = ml[BB * HH * NN + r];
    float M = fmaxf(a.x, b.x);
    float c0 = fexp2(a.x - M), c1 = fexp2(b.x - M);
    float inv = 1.f / (c0 * a.y + c1 * b.y);
    const float* p0 = opart + (size_t)r * VD + d0;
    const float* p1 = p0 + (size_t)(BB * HH) * NN * VD;
    float4 x0 = *(const float4*)p0;
    float4 x1 = *(const float4*)(p0 + 4);
    float4 y0 = *(const float4*)p1;
    float4 y1 = *(const float4*)(p1 + 4);
    const int bh = r >> 11, n = r & (NN - 1);
    float* op = out + ((size_t)(bh >> 3) * NN + n) * (HH * VD) + (bh & 7) * VD + d0;
    float4 o0, o1;
    o0.x = gelu_exact((c0 * x0.x + c1 * y0.x) * inv);
    o0.y = gelu_exact((c0 * x0.y + c1 * y0.y) * inv);
    o0.z = gelu_exact((c0 * x0.z + c1 * y0.z) * inv);
    o0.w = gelu_exact((c0 * x0.w + c1 * y0.w) * inv);
    o1.x = gelu_exact((c0 * x1.x + c1 * y1.x) * inv);
    o1.y = gelu_exact((c0 * x1.y + c1 * y1.y) * inv);
    o1.z = gelu_exact((c0 * x1.z + c1 * y1.z) * inv);
    o1.w = gelu_exact((c0 * x1.w + c1 * y1.w) * inv);
    *(float4*)op = o0;
    *(float4*)(op + 4) = o1;
}

// ---------------------------------------------------------------------------
extern "C" void kernel_launch(void* const* d_in, const int* in_sizes, int n_in,
                              void* d_out, int out_size, void* d_ws, size_t ws_size,
                              hipStream_t stream)
{
    const float* x  = (const float*)d_in[0];
    const float* qw = (const float*)d_in[1];
    const float* kw = (const float*)d_in[2];
    const float* vw = (const float*)d_in[3];
    float* out = (float*)d_out;

    // workspace layout
    _Float16* wt  = (_Float16*)d_ws;            // [3][H][VD][D]   =  786432 halves
    _Float16* xhp = wt  + 786432;               // [B*N][D]        = 2097152
    _Float16* qsp = xhp + 2097152;
    _Float16* kbp = qsp + 2097152;
    _Float16* vtp = kbp + 2097152;
    float*  opart = (float*)(vtp + 2097152);    // [2][16][2048][64] f32 = 16MB
    float2* mlp   = (float2*)(opart + (size_t)SPLIT * BB * HH * NN * VD);  // 512KB

    hipLaunchKernelGGL(prep_kernel, dim3(192 + 1024), dim3(256), 0, stream,
                       x, qw, kw, vw, wt, xhp);
    hipLaunchKernelGGL(qkv_proj_kernel, dim3(512), dim3(256), 0, stream,
                       xhp, wt, qsp, kbp, vtp);
    hipLaunchKernelGGL(attn_kernel, dim3(512), dim3(256), 0, stream,
                       qsp, kbp, vtp, opart, mlp);
    hipLaunchKernelGGL(combine_kernel, dim3(BB * HH * NN / 32), dim3(256), 0, stream,
                       opart, mlp, out);
}

// Round 6
// 60.561 us; speedup vs baseline: 3.0063x; 1.0347x over previous
//
#include <hip/hip_runtime.h>
#include <hip/hip_bf16.h>
#include <math.h>

// Problem constants
#define BB 2
#define NN 2048
#define DD 512
#define HH 8
#define VD 64
#define SPLIT 2
#define KVH (NN / SPLIT)      // 1024 kv per split block
#define NITER (KVH / 64)      // 16

typedef _Float16 half8 __attribute__((ext_vector_type(8)));
typedef _Float16 half4 __attribute__((ext_vector_type(4)));
typedef float f32x4 __attribute__((ext_vector_type(4)));

#define GLDS16(gp, lp) __builtin_amdgcn_global_load_lds( \
    (const __attribute__((address_space(1))) void*)(gp), \
    (__attribute__((address_space(3))) void*)(lp), 16, 0, 0)

__device__ __forceinline__ float fexp2(float x) {
#if __has_builtin(__builtin_amdgcn_exp2f)
    return __builtin_amdgcn_exp2f(x);
#else
    return exp2f(x);
#endif
}

// Stage 8 rows x 64 f16 cols (1KB) from global into LDS linear, source
// pre-swizzled so a swizzled read sees logical layout (T2 both-sides).
__device__ __forceinline__ void stage8(const _Float16* gsrc, size_t ldg, int r0,
                                       _Float16* lbase, int lane) {
    int r8 = lane >> 3;
    int ce = ((lane & 7) ^ r8) << 3;
    const _Float16* g = gsrc + (size_t)(r0 + r8) * ldg + ce;
    GLDS16(g, lbase);
}

// Swizzled half8 read: logical (row, col-byte cb) of a [*][128B] tile.
__device__ __forceinline__ half8 frag_ld(const _Float16* tile, int row, int cb) {
    int off = row * 128 + (cb ^ ((row & 7) << 4));
    return *(const half8*)((const char*)tile + off);
}

__device__ __forceinline__ float gelu_exact(float v) {
    return 0.5f * v * (1.f + erff(v * 0.70710678118654752f));
}

// ---------------------------------------------------------------------------
// prep: blocks 0..191: weight transpose fp32 [H][D][VD] -> f16 Wt[3][H][VD][D]
//       blocks 192..1215: X fp32 -> f16 cast
// ---------------------------------------------------------------------------
__global__ __launch_bounds__(256) void prep_kernel(
    const float* __restrict__ x,
    const float* __restrict__ qw, const float* __restrict__ kw,
    const float* __restrict__ vw,
    _Float16* __restrict__ wt, _Float16* __restrict__ xh)
{
    __shared__ float ls[64][65];
    const int t = threadIdx.x;
    const int bid = blockIdx.x;
    if (bid < 192) {
        const int kc = bid & 7, h = (bid >> 3) & 7, ty = bid >> 6;
        const float* src = (ty == 0) ? qw : (ty == 1) ? kw : vw;
#pragma unroll
        for (int j = 0; j < 4; ++j) {
            int idx = t + 256 * j;
            int k = idx >> 4, o4 = idx & 15;
            float4 v = *(const float4*)(src + ((size_t)(h * DD + kc * 64 + k) * VD + o4 * 4));
            ls[k][o4 * 4 + 0] = v.x; ls[k][o4 * 4 + 1] = v.y;
            ls[k][o4 * 4 + 2] = v.z; ls[k][o4 * 4 + 3] = v.w;
        }
        __syncthreads();
#pragma unroll
        for (int j = 0; j < 4; ++j) {
            int idx = t + 256 * j;
            int o = idx >> 4, k4 = idx & 15;
            half4 hv;
#pragma unroll
            for (int i = 0; i < 4; ++i) hv[i] = (_Float16)ls[k4 * 4 + i][o];
            *(half4*)(wt + ((size_t)(ty * HH + h) * VD + o) * DD + kc * 64 + k4 * 4) = hv;
        }
    } else {
        size_t idx = ((size_t)(bid - 192) * 256 + t) * 8;
        float4 a = *(const float4*)(x + idx);
        float4 b = *(const float4*)(x + idx + 4);
        half8 hv;
        hv[0] = (_Float16)a.x; hv[1] = (_Float16)a.y;
        hv[2] = (_Float16)a.z; hv[3] = (_Float16)a.w;
        hv[4] = (_Float16)b.x; hv[5] = (_Float16)b.y;
        hv[6] = (_Float16)b.z; hv[7] = (_Float16)b.w;
        *(half8*)(xh + idx) = hv;
    }
}

// ---------------------------------------------------------------------------
// QKV projection (Q pre-scale folds softmax 1/8 AND log2(e)).
// ---------------------------------------------------------------------------
__global__ __launch_bounds__(256) void qkv_proj_kernel(
    const _Float16* __restrict__ xh,
    const _Float16* __restrict__ wt,
    _Float16* __restrict__ qsp,
    _Float16* __restrict__ kbp,
    _Float16* __restrict__ vtp)
{
    __shared__ __align__(16) _Float16 xls[2][4096];
    __shared__ __align__(16) _Float16 wls[2][12288];
    const int t = threadIdx.x;
    const int wave = t >> 6, lane = t & 63;
    const int lq = lane & 15, g = lane >> 4;
    const int bid = blockIdx.x;
    const int h = bid & 7;
    const int m0 = (bid >> 3) * 64;
    const int rbase = 32 * (wave >> 1);
    const int cbase = 96 * (wave & 1);

    f32x4 acc[2][6];
#pragma unroll
    for (int a = 0; a < 2; ++a)
#pragma unroll
        for (int c = 0; c < 6; ++c) acc[a][c] = (f32x4){0.f, 0.f, 0.f, 0.f};

    auto stage = [&](int buf, int ks) {
#pragma unroll
        for (int j = 0; j < 2; ++j) {
            int i = wave * 2 + j;
            stage8(xh + (size_t)m0 * DD + ks * 64, DD, i * 8, &xls[buf][i * 512], lane);
        }
#pragma unroll
        for (int j = 0; j < 6; ++j) {
            int i = wave * 6 + j;
            int ty = i >> 3;
            int ol = (i & 7) * 8;
            stage8(wt + ((size_t)(ty * HH + h) * VD + ol) * DD + ks * 64, DD, 0,
                   &wls[buf][i * 512], lane);
        }
    };

    stage(0, 0);
    __syncthreads();
    int buf = 0;
    for (int ks = 0; ks < 8; ++ks) {
        if (ks < 7) stage(buf ^ 1, ks + 1);
        half8 af[2][2];
#pragma unroll
        for (int amt = 0; amt < 2; ++amt) {
            af[amt][0] = frag_ld(xls[buf], rbase + amt * 16 + lq, 16 * g);
            af[amt][1] = frag_ld(xls[buf], rbase + amt * 16 + lq, 64 + 16 * g);
        }
#pragma unroll
        for (int ct = 0; ct < 6; ++ct) {
            int wr = cbase + ct * 16 + lq;
            half8 bf0 = frag_ld(wls[buf], wr, 16 * g);
            half8 bf1 = frag_ld(wls[buf], wr, 64 + 16 * g);
#pragma unroll
            for (int amt = 0; amt < 2; ++amt) {
                acc[amt][ct] = __builtin_amdgcn_mfma_f32_16x16x32_f16(af[amt][0], bf0, acc[amt][ct], 0, 0, 0);
                acc[amt][ct] = __builtin_amdgcn_mfma_f32_16x16x32_f16(af[amt][1], bf1, acc[amt][ct], 0, 0, 0);
            }
        }
        __syncthreads();
        buf ^= 1;
    }

#pragma unroll
    for (int ct = 0; ct < 6; ++ct) {
        int gcol = cbase + ct * 16 + lq;
        int ty = gcol >> 6, o = gcol & 63;
#pragma unroll
        for (int amt = 0; amt < 2; ++amt) {
#pragma unroll
            for (int i = 0; i < 4; ++i) {
                int ng = m0 + rbase + amt * 16 + 4 * g + i;
                int b = ng >> 11, nb = ng & (NN - 1);
                size_t bh = (size_t)(b * HH + h);
                float v = acc[amt][ct][i];
                if (ty == 0)      qsp[(bh * NN + nb) * VD + o] = (_Float16)(v * 0.18033688011112042f);
                else if (ty == 1) kbp[(bh * NN + nb) * VD + o] = (_Float16)v;
                else              vtp[(bh * VD + o) * NN + nb] = (_Float16)v;
            }
        }
    }
}

// ---------------------------------------------------------------------------
// Flash attention, split-kv, 32 q per wave, REGISTER-RESIDENT P.
// kv-enumeration permutation: K LDS row r holds global kv pi(r),
//   pi(16mt+4g+i) = 16g+4mt+i, and V LDS col c holds global kv
//   16*((c>>3)&3) + 8*(c>>5) + (c&7). Then the lane's post-softmax S values
//   pack directly into the PV B-fragment (no LDS P roundtrip, no shuffles).
// Grid 512 = 8 XCD x 4 (s,bh) x 16 q-tiles. LDS 32KB.
// ---------------------------------------------------------------------------
__global__ __launch_bounds__(256, 2) void attn_kernel(
    const _Float16* __restrict__ qs,   // [BH][N][VD], scaled log2e/8
    const _Float16* __restrict__ kb,   // [BH][N][VD]
    const _Float16* __restrict__ vt,   // [BH][VD][N]
    float* __restrict__ opart,         // [SPLIT][BH][N][VD] f32
    float2* __restrict__ ml)           // [SPLIT][BH][N] (m, l)
{
    __shared__ __align__(16) _Float16 kls[2][4096];   // [kv-row=64][d=64] swizzled, rows pi-permuted
    __shared__ __align__(16) _Float16 vls[2][4096];   // [d=64][kv=64] swizzled, cols rho-permuted
    const int t = threadIdx.x;
    const int wave = t >> 6, lane = t & 63;
    const int lq = lane & 15, g = lane >> 4;
    const int bid = blockIdx.x;
    const int xcd = bid & 7;
    const int idx = bid >> 3;                 // 0..63
    const int sbh = (idx >> 4) * 8 + xcd;     // 0..31, (s,bh) pinned to one XCD
    const int s = sbh >> 4, bh = sbh & 15;
    const int qt = idx & 15;                  // 16 q-tiles of 128 rows
    const int qbase = qt * 128 + wave * 32;
    const int kvs = s * KVH;

    // Q fragments: 2 q-halves x 2 k-slices
    half8 qf[2][2];
#pragma unroll
    for (int qh = 0; qh < 2; ++qh) {
        const _Float16* qp = qs + ((size_t)bh * NN + qbase + qh * 16 + lq) * VD + 8 * g;
        qf[qh][0] = *(const half8*)qp;
        qf[qh][1] = *(const half8*)(qp + 32);
    }

    // --- staging source addresses (lane-resolved, loop-invariant) ---
    const int r8 = lane >> 3;
    const int dchunk = (lane & 7) ^ r8;            // XOR bank-swizzle chunk
    // K: LDS row (16w + 8c + r8) <- global kv row pi = 32c + 16*(r8>>2) + 4w + (r8&3)
    const int krow0 = 16 * (r8 >> 2) + 4 * wave + (r8 & 3);
    const _Float16* kgA = kb + (size_t)bh * NN * VD + (size_t)(kvs + krow0) * VD + dchunk * 8;
    // V: LDS row d = 16w + 8c + r8 (linear); logical chunk m=dchunk holds kv
    //    start 16*(m&3) + 8*(m>>2), 8 contiguous.
    const int kvst = 16 * (dchunk & 3) + 8 * (dchunk >> 2);
    const _Float16* vgA = vt + (size_t)bh * VD * NN + (size_t)(wave * 16 + r8) * NN + kvs + kvst;

    f32x4 oacc[2][4];
#pragma unroll
    for (int qh = 0; qh < 2; ++qh)
#pragma unroll
        for (int mt = 0; mt < 4; ++mt) oacc[qh][mt] = (f32x4){0.f, 0.f, 0.f, 0.f};
    float mrun[2] = {-INFINITY, -INFINITY};
    float lsum[2] = {0.f, 0.f};               // lane-partial; reduced once at end

    auto stagekv = [&](int buf, int itn) {
        const _Float16* kp = kgA + (size_t)itn * (64 * VD);
        GLDS16(kp,           &kls[buf][wave * 1024]);
        GLDS16(kp + 32 * VD, &kls[buf][wave * 1024 + 512]);
        const _Float16* vp = vgA + itn * 64;
        GLDS16(vp,           &vls[buf][wave * 1024]);
        GLDS16(vp + 8 * NN,  &vls[buf][wave * 1024 + 512]);
    };

    stagekv(0, 0);
    __syncthreads();

#define AT_BODY(BUF, ITN)                                                        \
    {                                                                            \
        if ((ITN) < NITER - 1) stagekv((BUF) ^ 1, (ITN) + 1);                    \
        f32x4 sv[2][4];                                                          \
        __builtin_amdgcn_s_setprio(1);                                           \
        _Pragma("unroll") for (int mt = 0; mt < 4; ++mt) {                       \
            half8 k0 = frag_ld(kls[BUF], mt * 16 + lq, 16 * g);                  \
            half8 k1 = frag_ld(kls[BUF], mt * 16 + lq, 64 + 16 * g);             \
            _Pragma("unroll") for (int qh = 0; qh < 2; ++qh) {                   \
                sv[qh][mt] = (f32x4){0.f, 0.f, 0.f, 0.f};                        \
                sv[qh][mt] = __builtin_amdgcn_mfma_f32_16x16x32_f16(k0, qf[qh][0], sv[qh][mt], 0, 0, 0); \
                sv[qh][mt] = __builtin_amdgcn_mfma_f32_16x16x32_f16(k1, qf[qh][1], sv[qh][mt], 0, 0, 0); \
            }                                                                    \
        }                                                                        \
        __builtin_amdgcn_s_setprio(0);                                           \
        half8 pf[2][2];                                                          \
        _Pragma("unroll") for (int qh = 0; qh < 2; ++qh) {                       \
            float a0 = fmaxf(fmaxf(sv[qh][0][0], sv[qh][0][1]), fmaxf(sv[qh][0][2], sv[qh][0][3])); \
            float a1 = fmaxf(fmaxf(sv[qh][1][0], sv[qh][1][1]), fmaxf(sv[qh][1][2], sv[qh][1][3])); \
            float a2 = fmaxf(fmaxf(sv[qh][2][0], sv[qh][2][1]), fmaxf(sv[qh][2][2], sv[qh][2][3])); \
            float a3 = fmaxf(fmaxf(sv[qh][3][0], sv[qh][3][1]), fmaxf(sv[qh][3][2], sv[qh][3][3])); \
            float tmax = fmaxf(fmaxf(a0, a1), fmaxf(a2, a3));                    \
            tmax = fmaxf(tmax, __shfl_xor(tmax, 16, 64));                        \
            tmax = fmaxf(tmax, __shfl_xor(tmax, 32, 64));                        \
            if (__any(tmax > mrun[qh] + 8.f)) {                                  \
                float mnew = fmaxf(mrun[qh], tmax);                              \
                float corr = fexp2(mrun[qh] - mnew);                             \
                lsum[qh] *= corr;                                                \
                _Pragma("unroll") for (int mt = 0; mt < 4; ++mt)                 \
                    _Pragma("unroll") for (int i = 0; i < 4; ++i) oacc[qh][mt][i] *= corr; \
                mrun[qh] = mnew;                                                 \
            }                                                                    \
            _Pragma("unroll") for (int mt = 0; mt < 4; ++mt) {                   \
                _Pragma("unroll") for (int i = 0; i < 4; ++i) {                  \
                    float p = fexp2(sv[qh][mt][i] - mrun[qh]);                   \
                    lsum[qh] += p;                                               \
                    pf[qh][mt >> 1][(mt & 1) * 4 + i] = (_Float16)p;             \
                }                                                                \
            }                                                                    \
        }                                                                        \
        __builtin_amdgcn_s_setprio(1);                                           \
        _Pragma("unroll") for (int kc = 0; kc < 2; ++kc) {                       \
            _Pragma("unroll") for (int mt = 0; mt < 4; ++mt) {                   \
                half8 vf = frag_ld(vls[BUF], mt * 16 + lq, kc * 64 + 16 * g);    \
                oacc[0][mt] = __builtin_amdgcn_mfma_f32_16x16x32_f16(vf, pf[0][kc], oacc[0][mt], 0, 0, 0); \
                oacc[1][mt] = __builtin_amdgcn_mfma_f32_16x16x32_f16(vf, pf[1][kc], oacc[1][mt], 0, 0, 0); \
            }                                                                    \
        }                                                                        \
        __builtin_amdgcn_s_setprio(0);                                           \
        __syncthreads();                                                         \
    }

    for (int it = 0; it < NITER; it += 2) {
        AT_BODY(0, it);
        AT_BODY(1, it + 1);
    }
#undef AT_BODY

    // final lsum reduction over g-groups, then store partial O + (m, l)
#pragma unroll
    for (int qh = 0; qh < 2; ++qh) {
        float l = lsum[qh];
        l += __shfl_xor(l, 16, 64);
        l += __shfl_xor(l, 32, 64);
        float* op = opart + (((size_t)s * (BB * HH) + bh) * NN + qbase + qh * 16 + lq) * VD;
#pragma unroll
        for (int mt = 0; mt < 4; ++mt) {
            float4 r;
            r.x = oacc[qh][mt][0]; r.y = oacc[qh][mt][1];
            r.z = oacc[qh][mt][2]; r.w = oacc[qh][mt][3];
            *(float4*)(op + mt * 16 + 4 * g) = r;
        }
        if (g == 0) {
            float2 v; v.x = mrun[qh]; v.y = l;
            ml[((size_t)s * (BB * HH) + bh) * NN + qbase + qh * 16 + lq] = v;
        }
    }
}

// ---------------------------------------------------------------------------
// Combine split-kv partials + GELU. 32768 rows x 64 d. Block 256 = 32 rows.
// ---------------------------------------------------------------------------
__global__ __launch_bounds__(256) void combine_kernel(
    const float* __restrict__ opart, const float2* __restrict__ ml,
    float* __restrict__ out)
{
    const int t = threadIdx.x;
    const int r = blockIdx.x * 32 + (t >> 3);   // bh*2048 + n
    const int d0 = (t & 7) * 8;
    float2 a = ml[r];
    float2 b = ml[BB * HH * NN + r];
    float M = fmaxf(a.x, b.x);
    float c0 = fexp2(a.x - M), c1 = fexp2(b.x - M);
    float inv = 1.f / (c0 * a.y + c1 * b.y);
    const float* p0 = opart + (size_t)r * VD + d0;
    const float* p1 = p0 + (size_t)(BB * HH) * NN * VD;
    float4 x0 = *(const float4*)p0;
    float4 x1 = *(const float4*)(p0 + 4);
    float4 y0 = *(const float4*)p1;
    float4 y1 = *(const float4*)(p1 + 4);
    const int bh = r >> 11, n = r & (NN - 1);
    float* op = out + ((size_t)(bh >> 3) * NN + n) * (HH * VD) + (bh & 7) * VD + d0;
    float4 o0, o1;
    o0.x = gelu_exact((c0 * x0.x + c1 * y0.x) * inv);
    o0.y = gelu_exact((c0 * x0.y + c1 * y0.y) * inv);
    o0.z = gelu_exact((c0 * x0.z + c1 * y0.z) * inv);
    o0.w = gelu_exact((c0 * x0.w + c1 * y0.w) * inv);
    o1.x = gelu_exact((c0 * x1.x + c1 * y1.x) * inv);
    o1.y = gelu_exact((c0 * x1.y + c1 * y1.y) * inv);
    o1.z = gelu_exact((c0 * x1.z + c1 * y1.z) * inv);
    o1.w = gelu_exact((c0 * x1.w + c1 * y1.w) * inv);
    *(float4*)op = o0;
    *(float4*)(op + 4) = o1;
}

// ---------------------------------------------------------------------------
extern "C" void kernel_launch(void* const* d_in, const int* in_sizes, int n_in,
                              void* d_out, int out_size, void* d_ws, size_t ws_size,
                              hipStream_t stream)
{
    const float* x  = (const float*)d_in[0];
    const float* qw = (const float*)d_in[1];
    const float* kw = (const float*)d_in[2];
    const float* vw = (const float*)d_in[3];
    float* out = (float*)d_out;

    // workspace layout
    _Float16* wt  = (_Float16*)d_ws;            // [3][H][VD][D]   =  786432 halves
    _Float16* xhp = wt  + 786432;               // [B*N][D]        = 2097152
    _Float16* qsp = xhp + 2097152;
    _Float16* kbp = qsp + 2097152;
    _Float16* vtp = kbp + 2097152;
    float*  opart = (float*)(vtp + 2097152);    // [2][16][2048][64] f32 = 16MB
    float2* mlp   = (float2*)(opart + (size_t)SPLIT * BB * HH * NN * VD);  // 512KB

    hipLaunchKernelGGL(prep_kernel, dim3(192 + 1024), dim3(256), 0, stream,
                       x, qw, kw, vw, wt, xhp);
    hipLaunchKernelGGL(qkv_proj_kernel, dim3(512), dim3(256), 0, stream,
                       xhp, wt, qsp, kbp, vtp);
    hipLaunchKernelGGL(attn_kernel, dim3(512), dim3(256), 0, stream,
                       qsp, kbp, vtp, opart, mlp);
    hipLaunchKernelGGL(combine_kernel, dim3(BB * HH * NN / 32), dim3(256), 0, stream,
                       opart, mlp, out);
}